// Round 7
// baseline (70.789 us; speedup 1.0000x reference)
//
#include <hip/hip_runtime.h>

#define GAMMA 0.999f
#define LAMBD 0.7f
#define ALPHA 0.99f

constexpr int A_DIM = 64;
constexpr int CH    = 64;    // rows per block; nch = T/CH = 4096
constexpr int BLK   = 128;   // 2 waves; each wave computes 32 rows

// ---------------------------------------------------------------------------
// K1: one 128-thread block per 64-row chunk (32 rows per wave -> 32 waves/CU).
//  A: gathers split across the two waves (wave0: q,pi @ action; wave1: mu,
//     r_t, done).
//  B: dots. Wave w owns rows [w*32,(w+1)*32); 8 rows per step (sub=lane>>4,
//     li=lane&15, float4/lane, 2 interleaved groups); 16-lane butterflies ->
//     v_t, v_tp1; coalesced float4 advantages write.
//  C: wave0 only, lane owns row lane: affine F=(Fa,Fb), wave-shuffle suffix
//     scan; emit comb[t]={U,W} (targets[t] = U + W*ye(chunk)) and cab[chunk].
// ---------------------------------------------------------------------------
__global__ __launch_bounds__(BLK, 8)
void k_main(const float* __restrict__ q, const float* __restrict__ q_tar,
            const float* __restrict__ pi, const int* __restrict__ a_t,
            const float* __restrict__ r_t, const float* __restrict__ mu_t,
            const int* __restrict__ done_t,
            float* __restrict__ adv_out,
            float2* __restrict__ comb, float2* __restrict__ cab)
{
    __shared__ float sQa[CH], sPa[CH], sMa[CH], sKm[CH], sRt[CH];
    __shared__ float sV[CH], sVp[CH];

    const int tid  = threadIdx.x;
    const int wave = tid >> 6, lane = tid & 63;
    const int sub  = lane >> 4, li = lane & 15;
    const int R0   = blockIdx.x * CH;

    // ---- phase A: action gathers + scalars, split across waves
    {
        int r = R0 + lane;
        int a = a_t[r];
        if (wave == 0) {
            sQa[lane] = q[r * A_DIM + a];
            sPa[lane] = pi[r * A_DIM + a];
        } else {
            sMa[lane] = mu_t[r * A_DIM + a];
            sRt[lane] = r_t[r];
            sKm[lane] = 1.0f - (float)done_t[r];
        }
    }

    // ---- phase B: dots + advantages (4 iterations x 8 rows per wave)
    #pragma unroll 2
    for (int i = 0; i < 4; ++i) {
        int lrowA = wave * 32 + i * 8 + sub;
        int lrowB = lrowA + 4;
        int gA = (R0 + lrowA) * A_DIM + li * 4;
        int gB = (R0 + lrowB) * A_DIM + li * 4;

        float4 piA  = *(const float4*)&pi[gA];
        float4 qA   = *(const float4*)&q[gA];
        float4 pipA = *(const float4*)&pi[gA + A_DIM];
        float4 qpA  = *(const float4*)&q_tar[gA + A_DIM];
        float4 piB  = *(const float4*)&pi[gB];
        float4 qB   = *(const float4*)&q[gB];
        float4 pipB = *(const float4*)&pi[gB + A_DIM];
        float4 qpB  = *(const float4*)&q_tar[gB + A_DIM];

        float s0A = piA.x*qA.x + piA.y*qA.y + piA.z*qA.z + piA.w*qA.w;
        float s1A = pipA.x*qpA.x + pipA.y*qpA.y + pipA.z*qpA.z + pipA.w*qpA.w;
        float s0B = piB.x*qB.x + piB.y*qB.y + piB.z*qB.z + piB.w*qB.w;
        float s1B = pipB.x*qpB.x + pipB.y*qpB.y + pipB.z*qpB.z + pipB.w*qpB.w;
        #pragma unroll
        for (int off = 1; off < 16; off <<= 1) {
            s0A += __shfl_xor(s0A, off);
            s1A += __shfl_xor(s1A, off);
            s0B += __shfl_xor(s0B, off);
            s1B += __shfl_xor(s1B, off);
        }

        float4 advA, advB;
        advA.x = (1.0f - ALPHA) * (qA.x - s0A);
        advA.y = (1.0f - ALPHA) * (qA.y - s0A);
        advA.z = (1.0f - ALPHA) * (qA.z - s0A);
        advA.w = (1.0f - ALPHA) * (qA.w - s0A);
        advB.x = (1.0f - ALPHA) * (qB.x - s0B);
        advB.y = (1.0f - ALPHA) * (qB.y - s0B);
        advB.z = (1.0f - ALPHA) * (qB.z - s0B);
        advB.w = (1.0f - ALPHA) * (qB.w - s0B);
        *(float4*)&adv_out[gA] = advA;
        *(float4*)&adv_out[gB] = advB;

        if (li == 0) {
            sV[lrowA] = s0A;  sVp[lrowA] = s1A;
            sV[lrowB] = s0B;  sVp[lrowB] = s1B;
        }
    }
    __syncthreads();

    // ---- phase C: wave 0 only; lane owns row lane
    if (wave == 0) {
        float s0    = sV[lane],  s1 = sVp[lane];
        float kmask = sKm[lane];
        float qa    = sQa[lane];
        float rho   = sPa[lane] / sMa[lane];
        float est = sRt[lane] + kmask * (GAMMA * s1);
        float td  = est - qa;
        float c   = LAMBD * fminf(fmaxf(rho, 0.0f), 1.0f);
        float Fa  = (LAMBD * GAMMA) * rho * td;   // y_t = Fa + Fb*y_{t+1}
        float Fb  = kmask * (GAMMA * c);
        float E   = est + ALPHA * (qa - s0);      // targets = E + kmask*y_{t+1}

        float Ai = Fa, Bi = Fb;                   // inclusive suffix scan
        #pragma unroll
        for (int off = 1; off < 64; off <<= 1) {
            float An = __shfl_down(Ai, off);
            float Bn = __shfl_down(Bi, off);
            if (lane + off < 64) { Ai += Bi * An; Bi *= Bn; }
        }
        float Xa = __shfl_down(Ai, 1);            // exclusive
        float Xb = __shfl_down(Bi, 1);
        if (lane == 63) { Xa = 0.0f; Xb = 1.0f; }
        comb[R0 + lane] = make_float2(E + kmask * Xa, kmask * Xb);
        if (lane == 0) cab[blockIdx.x] = make_float2(Ai, Bi);
    }
}

// ---------------------------------------------------------------------------
// K2: 64-lane blocks, each finalizes 2 chunks (128 rows). Redundant suffix
// scan of the 4096 chunk composites: lane folds 64 chunks (32 float4, L2-hot),
// wave suffix scan over 64 supers, uniform <=64-step tail fold for the
// boundary after chunk 2b+1; boundary after chunk 2b derived via cab[2b+1].
// ---------------------------------------------------------------------------
__global__ __launch_bounds__(64, 8)
void k_fin(const float2* __restrict__ comb, const float2* __restrict__ cab,
           float* __restrict__ targets, int nch)
{
    const int lane = threadIdx.x, bid = blockIdx.x;

    // fold 64 consecutive chunks (outer-first): super `lane`
    const float4* cab4 = (const float4*)cab;
    float A = 0.0f, B = 1.0f;
    #pragma unroll 8
    for (int j = 0; j < 32; ++j) {
        float4 u = cab4[lane * 32 + j];
        A += B * u.x; B *= u.y;
        A += B * u.z; B *= u.w;
    }

    // inclusive suffix scan over 64 supers
    float Ai = A, Bi = B;
    #pragma unroll
    for (int off = 1; off < 64; off <<= 1) {
        float An = __shfl_down(Ai, off);
        float Bn = __shfl_down(Bi, off);
        if (lane + off < 64) { Ai += Bi * An; Bi *= Bn; }
    }
    float Xa = __shfl_down(Ai, 1);   // exclusive: suffix from super lane+1
    float Xb = __shfl_down(Bi, 1);
    if (lane == 63) { Xa = 0.0f; Xb = 1.0f; }

    // ye2 = y at start of chunk c1 = 2*bid+2 (0 if past the end)
    float ye2;
    int c1 = 2 * bid + 2;
    if (c1 >= nch) {
        ye2 = 0.0f;
    } else {
        int jq = c1 >> 6;
        float Aa = __shfl(Xa, jq);   // suffix over supers > jq
        float Bb = __shfl(Xb, jq);
        int end = jq * 64 + 63;      // fold chunks end..c1 (uniform loop)
        for (int k = end; k >= c1; --k) {
            float2 cv = cab[k];
            Aa = cv.x + cv.y * Aa;
            Bb = cv.y * Bb;
        }
        ye2 = Aa;
    }
    // ye1 = y at start of chunk 2b+1 = cab[2b+1] applied to ye2
    float2 cm1 = cab[2 * bid + 1];
    float ye1 = cm1.x + cm1.y * ye2;

    int r0 = bid * 128;
    float2 uw0 = comb[r0 + lane];
    targets[r0 + lane] = uw0.x + uw0.y * ye1;
    float2 uw1 = comb[r0 + 64 + lane];
    targets[r0 + 64 + lane] = uw1.x + uw1.y * ye2;
}

extern "C" void kernel_launch(void* const* d_in, const int* in_sizes, int n_in,
                              void* d_out, int out_size, void* d_ws, size_t ws_size,
                              hipStream_t stream) {
    const float* q      = (const float*)d_in[0];
    const float* q_tar  = (const float*)d_in[1];
    const float* pi     = (const float*)d_in[2];
    const int*   a_t    = (const int*)  d_in[3];
    const float* r_t    = (const float*)d_in[4];
    const float* mu_t   = (const float*)d_in[5];
    const int*   done_t = (const int*)  d_in[6];

    const int T   = in_sizes[3];         // 262144
    const int nch = T / CH;              // 4096

    float* targets = (float*)d_out;          // T floats
    float* adv     = (float*)d_out + T;      // T*A floats

    char* ws = (char*)d_ws;
    float2* comb = (float2*)ws;              ws += (size_t)8 * T;
    float2* cab  = (float2*)ws;

    k_main<<<nch, BLK, 0, stream>>>(q, q_tar, pi, a_t, r_t, mu_t, done_t,
                                    adv, comb, cab);
    k_fin<<<nch / 2, 64, 0, stream>>>(comb, cab, targets, nch);
}

// Round 9
// 63.291 us; speedup vs baseline: 1.1185x; 1.1185x over previous
//
#include <hip/hip_runtime.h>

#define GAMMA 0.999f
#define LAMBD 0.7f
#define ALPHA 0.99f

constexpr int A_DIM = 64;
constexpr int CH    = 128;   // rows per block; nch = T/CH = 2048
constexpr int BLK   = 256;   // 4 waves; each wave computes 32 rows

typedef float fx4 __attribute__((ext_vector_type(4)));   // native vec for NT stores

__device__ __forceinline__ float dot4(const float4& a, const float4& b) {
    return a.x*b.x + a.y*b.y + a.z*b.z + a.w*b.w;
}

__device__ __forceinline__ void nt_store4(float* p, float x, float y, float z, float w) {
    fx4 v = { x, y, z, w };
    __builtin_nontemporal_store(v, (fx4*)p);
}

// ---------------------------------------------------------------------------
// K1: one 256-thread block per 128-row chunk.
//  A: action gathers + scalars, split across thread halves.
//  B: dots, software-pipelined: prefetch iter i+1's 8 float4 loads before
//     consuming iter i (keeps loads in flight across the shuffle chains).
//     Wave w owns rows [w*32,(w+1)*32); 8 rows per iter (sub=lane>>4 picks
//     row, li=lane&15 the 4-col slice; 2 groups of 4 rows).
//  C: waves 0,1 (lane owns row wave*64+lane): affine F=(Fa,Fb), wave-shuffle
//     suffix scan + cross-wave combine. comb[t]={U,W}, cab[chunk]=composite.
// ---------------------------------------------------------------------------
__global__ __launch_bounds__(BLK, 4)
void k_main(const float* __restrict__ q, const float* __restrict__ q_tar,
            const float* __restrict__ pi, const int* __restrict__ a_t,
            const float* __restrict__ r_t, const float* __restrict__ mu_t,
            const int* __restrict__ done_t,
            float* __restrict__ adv_out,
            float2* __restrict__ comb, float2* __restrict__ cab)
{
    __shared__ float sQa[CH], sPa[CH], sMa[CH], sKm[CH], sRt[CH];
    __shared__ float sV[CH], sVp[CH];
    __shared__ float sWA[2], sWB[2];

    const int tid  = threadIdx.x;
    const int wave = tid >> 6, lane = tid & 63;
    const int sub  = lane >> 4, li = lane & 15;
    const int R0   = blockIdx.x * CH;

    // ---- phase A: gathers + scalars (split across the two halves)
    if (tid < CH) {
        int r = R0 + tid;
        int a = a_t[r];
        sQa[tid] = q[r * A_DIM + a];
        sPa[tid] = pi[r * A_DIM + a];
    } else {
        int row = tid - CH;
        int r = R0 + row;
        int a = a_t[r];
        sMa[row] = mu_t[r * A_DIM + a];
        sRt[row] = r_t[r];
        sKm[row] = 1.0f - (float)done_t[r];
    }

    // ---- phase B: software-pipelined dots + advantages
    const int lrow0 = wave * 32 + sub;
    float4 piA, qA, pipA, qpA, piB, qB, pipB, qpB;
    {
        int gA = (R0 + lrow0) * A_DIM + li * 4;
        int gB = gA + 4 * A_DIM;
        piA  = *(const float4*)&pi[gA];
        qA   = *(const float4*)&q[gA];
        pipA = *(const float4*)&pi[gA + A_DIM];
        qpA  = *(const float4*)&q_tar[gA + A_DIM];
        piB  = *(const float4*)&pi[gB];
        qB   = *(const float4*)&q[gB];
        pipB = *(const float4*)&pi[gB + A_DIM];
        qpB  = *(const float4*)&q_tar[gB + A_DIM];
    }
    #pragma unroll
    for (int i = 0; i < 4; ++i) {
        float4 npiA, nqA, npipA, nqpA, npiB, nqB, npipB, nqpB;
        if (i < 3) {
            int gA = (R0 + lrow0 + (i + 1) * 8) * A_DIM + li * 4;
            int gB = gA + 4 * A_DIM;
            npiA  = *(const float4*)&pi[gA];
            nqA   = *(const float4*)&q[gA];
            npipA = *(const float4*)&pi[gA + A_DIM];
            nqpA  = *(const float4*)&q_tar[gA + A_DIM];
            npiB  = *(const float4*)&pi[gB];
            nqB   = *(const float4*)&q[gB];
            npipB = *(const float4*)&pi[gB + A_DIM];
            nqpB  = *(const float4*)&q_tar[gB + A_DIM];
        }

        int lrowA = lrow0 + i * 8;
        int lrowB = lrowA + 4;
        int gA = (R0 + lrowA) * A_DIM + li * 4;
        int gB = (R0 + lrowB) * A_DIM + li * 4;

        float s0A = dot4(piA, qA),  s1A = dot4(pipA, qpA);
        float s0B = dot4(piB, qB),  s1B = dot4(pipB, qpB);
        #pragma unroll
        for (int off = 1; off < 16; off <<= 1) {
            s0A += __shfl_xor(s0A, off);
            s1A += __shfl_xor(s1A, off);
            s0B += __shfl_xor(s0B, off);
            s1B += __shfl_xor(s1B, off);
        }

        nt_store4(&adv_out[gA],
                  (1.0f - ALPHA) * (qA.x - s0A), (1.0f - ALPHA) * (qA.y - s0A),
                  (1.0f - ALPHA) * (qA.z - s0A), (1.0f - ALPHA) * (qA.w - s0A));
        nt_store4(&adv_out[gB],
                  (1.0f - ALPHA) * (qB.x - s0B), (1.0f - ALPHA) * (qB.y - s0B),
                  (1.0f - ALPHA) * (qB.z - s0B), (1.0f - ALPHA) * (qB.w - s0B));

        if (li == 0) {
            sV[lrowA] = s0A;  sVp[lrowA] = s1A;
            sV[lrowB] = s0B;  sVp[lrowB] = s1B;
        }

        piA = npiA; qA = nqA; pipA = npipA; qpA = nqpA;
        piB = npiB; qB = nqB; pipB = npipB; qpB = nqpB;
    }
    __syncthreads();

    // ---- phase C: waves 0,1; lane owns row wave*64 + lane
    float Ai = 0.0f, Bi = 1.0f, Xa = 0.0f, Xb = 1.0f;
    float E = 0.0f, kmask = 0.0f;
    int   row = wave * 64 + lane;
    if (wave < 2) {
        float s0 = sV[row], s1 = sVp[row];
        kmask = sKm[row];
        float qa  = sQa[row];
        float rho = sPa[row] / sMa[row];
        float est = sRt[row] + kmask * (GAMMA * s1);
        float td  = est - qa;
        float c   = LAMBD * fminf(fmaxf(rho, 0.0f), 1.0f);
        float Fa  = (LAMBD * GAMMA) * rho * td;   // y_t = Fa + Fb*y_{t+1}
        float Fb  = kmask * (GAMMA * c);
        E = est + ALPHA * (qa - s0);              // targets = E + kmask*y_{t+1}

        Ai = Fa; Bi = Fb;                         // inclusive suffix scan
        #pragma unroll
        for (int off = 1; off < 64; off <<= 1) {
            float An = __shfl_down(Ai, off);
            float Bn = __shfl_down(Bi, off);
            if (lane + off < 64) { Ai += Bi * An; Bi *= Bn; }
        }
        if (lane == 0) { sWA[wave] = Ai; sWB[wave] = Bi; }
        Xa = __shfl_down(Ai, 1);                  // exclusive
        Xb = __shfl_down(Bi, 1);
        if (lane == 63) { Xa = 0.0f; Xb = 1.0f; }
    }
    __syncthreads();
    if (wave < 2) {
        if (wave == 0) {                          // append wave 1's composite
            Xa = Xa + Xb * sWA[1];
            Xb = Xb * sWB[1];
        }
        comb[R0 + row] = make_float2(E + kmask * Xa, kmask * Xb);
        if (tid == 0)
            cab[blockIdx.x] = make_float2(Ai + Bi * sWA[1], Bi * sWB[1]);
    }
}

// ---------------------------------------------------------------------------
// K2: each 128-thread block finalizes one 128-row chunk. Redundant suffix
// scan of nch=2048 chunk composites (16 KB, L2-hot): 16-chunk register fold
// per thread -> 128 supers -> wave scan + cross-wave combine; thread 0 folds
// the <=16-entry tail to get ye for this chunk.
// ---------------------------------------------------------------------------
__global__ __launch_bounds__(BLK / 2, 8)
void k_fin(const float2* __restrict__ comb, const float2* __restrict__ cab,
           float* __restrict__ targets, int nch)
{
    __shared__ float sXa[128], sXb[128];
    __shared__ float sWA[2], sWB[2];
    __shared__ float sYe;
    const int tid = threadIdx.x, bid = blockIdx.x;
    const int wave = tid >> 6, lane = tid & 63;

    // fold 16 consecutive chunks (8 float4 loads), outer-first order
    const float4* cab4 = (const float4*)cab;
    float A = 0.0f, B = 1.0f;
    #pragma unroll
    for (int j = 0; j < 8; ++j) {
        float4 u = cab4[tid * 8 + j];
        A += B * u.x; B *= u.y;
        A += B * u.z; B *= u.w;
    }

    // suffix scan over 128 supers: wave shuffle + cross-wave combine
    float Ai = A, Bi = B;
    #pragma unroll
    for (int off = 1; off < 64; off <<= 1) {
        float An = __shfl_down(Ai, off);
        float Bn = __shfl_down(Bi, off);
        if (lane + off < 64) { Ai += Bi * An; Bi *= Bn; }
    }
    if (lane == 0) { sWA[wave] = Ai; sWB[wave] = Bi; }
    float Xa = __shfl_down(Ai, 1);
    float Xb = __shfl_down(Bi, 1);
    if (lane == 63) { Xa = 0.0f; Xb = 1.0f; }
    __syncthreads();
    if (wave == 0) {
        Xa = Xa + Xb * sWA[1];
        Xb = Xb * sWB[1];
    }
    sXa[tid] = Xa; sXb[tid] = Xb;   // exclusive suffix over supers > tid
    __syncthreads();

    if (tid == 0) {
        int c1 = bid + 1;                  // suffix over chunks c1..nch-1
        float ye;
        if (c1 >= nch) {
            ye = 0.0f;
        } else {
            int jq = c1 >> 4;
            float Aa = sXa[jq], Bb = sXb[jq];     // suffix over supers > jq
            for (int k2 = 16 * jq + 15; k2 >= c1; --k2) {
                float2 cv = cab[k2];
                Aa = cv.x + cv.y * Aa;
                Bb = cv.y * Bb;
            }
            ye = Aa;
        }
        sYe = ye;
    }
    __syncthreads();

    float2 uw = comb[bid * CH + tid];
    __builtin_nontemporal_store(uw.x + uw.y * sYe, &targets[bid * CH + tid]);
}

extern "C" void kernel_launch(void* const* d_in, const int* in_sizes, int n_in,
                              void* d_out, int out_size, void* d_ws, size_t ws_size,
                              hipStream_t stream) {
    const float* q      = (const float*)d_in[0];
    const float* q_tar  = (const float*)d_in[1];
    const float* pi     = (const float*)d_in[2];
    const int*   a_t    = (const int*)  d_in[3];
    const float* r_t    = (const float*)d_in[4];
    const float* mu_t   = (const float*)d_in[5];
    const int*   done_t = (const int*)  d_in[6];

    const int T   = in_sizes[3];         // 262144
    const int nch = T / CH;              // 2048

    float* targets = (float*)d_out;          // T floats
    float* adv     = (float*)d_out + T;      // T*A floats

    char* ws = (char*)d_ws;
    float2* comb = (float2*)ws;              ws += (size_t)8 * T;
    float2* cab  = (float2*)ws;

    k_main<<<nch, BLK, 0, stream>>>(q, q_tar, pi, a_t, r_t, mu_t, done_t,
                                    adv, comb, cab);
    k_fin<<<nch, BLK / 2, 0, stream>>>(comb, cab, targets, nch);
}